// Round 6
// baseline (249.672 us; speedup 1.0000x reference)
//
#include <hip/hip_runtime.h>
#include <stdint.h>

#define TOKENS 65536
#define CDIM 384
#define NEXP 5
#define NPAIR 10
#define CAP 8192               // per-bucket capacity; E[cnt]=6554, sigma~77 -> 21-sigma margin
#define NBLK 1024              // router blocks (64 tokens each)
#define WE_STRIDE (CDIM * CDIM)

typedef __attribute__((ext_vector_type(8))) short short8;
typedef __attribute__((ext_vector_type(4))) float floatx4;

// unordered expert pair id p -> (a,b), a<b; p = a*4 - a*(a-1)/2 + (b-a-1)
__constant__ int PAIR_A[NPAIR] = {0, 0, 0, 0, 1, 1, 1, 2, 2, 3};
__constant__ int PAIR_B[NPAIR] = {1, 2, 3, 4, 2, 3, 4, 3, 4, 4};

__device__ inline unsigned short f2bf(float f) {
    union { float f; uint32_t u; } v; v.f = f;
    uint32_t r = v.u + 0x7fffu + ((v.u >> 16) & 1u);   // RNE for normal values
    return (unsigned short)(r >> 16);
}

__device__ inline void load_lds16(const void* g, void* l) {
    // async global->LDS, 16B/lane; dest = wave-uniform base + lane*16
    __builtin_amdgcn_global_load_lds((const __attribute__((address_space(1))) void*)g,
                                     (__attribute__((address_space(3))) void*)l, 16, 0, 0);
}

// ---------------- Kernel 1: router v7 — coalesced LDS-staged x (unchanged control) --
__global__ __launch_bounds__(256) void router_kernel(const float* __restrict__ x,
                                                     const float* __restrict__ Wg,
                                                     int* __restrict__ blkcnt,
                                                     int* __restrict__ tmeta,
                                                     float2* __restrict__ tgate) {
    __shared__ __align__(16) float  xs[64 * 129];        // 32.25 KB chunk buffer
    __shared__ __align__(16) float  wgs[CDIM * 8];       // padded stride 8, 12 KB
    __shared__ __align__(16) double part[4 * 64 * NEXP]; // 10 KB
    __shared__ __align__(16) double lg[64 * NEXP];       // 2.5 KB   (total ~56.8 KB)
    int t = threadIdx.x, lane = t & 63, w = t >> 6;
    int tok0 = blockIdx.x * 64;

    for (int i = t; i < CDIM * NEXP; i += 256) wgs[(i / NEXP) * 8 + (i % NEXP)] = Wg[i];

    int lrow = t >> 5, loff = (t & 31) * 4;              // 32 lanes cover one 512B row-chunk
    double p0 = 0, p1 = 0, p2 = 0, p3 = 0, p4 = 0;
    #pragma unroll
    for (int ch = 0; ch < 3; ++ch) {
        __syncthreads();                                 // prev-chunk readers done (+wgs at ch=0)
        #pragma unroll
        for (int r8 = 0; r8 < 8; ++r8) {
            int row = r8 * 8 + lrow;
            float4 v = *(const float4*)&x[(size_t)(tok0 + row) * CDIM + ch * 128 + loff];
            float* d = &xs[row * 129 + loff];
            d[0] = v.x; d[1] = v.y; d[2] = v.z; d[3] = v.w;
        }
        __syncthreads();                                 // chunk staged
        const float* xr = &xs[lane * 129 + w * 32];      // bank (lane+j)%32 -> conflict-free
        #pragma unroll
        for (int j = 0; j < 32; ++j) {
            int c = ch * 128 + w * 32 + j;               // wave-uniform -> wgs broadcast
            float4 w03 = *(const float4*)&wgs[c * 8];
            float  w4  = wgs[c * 8 + 4];
            double xd = (double)xr[j];
            p0 += xd * w03.x; p1 += xd * w03.y; p2 += xd * w03.z;
            p3 += xd * w03.w; p4 += xd * w4;
        }
    }
    double* pr = &part[(w * 64 + lane) * NEXP];
    pr[0] = p0; pr[1] = p1; pr[2] = p2; pr[3] = p3; pr[4] = p4;
    __syncthreads();

    for (int item = t; item < 64 * NEXP; item += 256) {
        lg[item] = part[item] + part[320 + item] + part[640 + item] + part[960 + item];
    }
    __syncthreads();

    if (t < 64) {                                        // wave 0: whole block's tokens
        double pa[NEXP];
        #pragma unroll
        for (int e = 0; e < NEXP; ++e) pa[e] = lg[t * NEXP + e];
        int i0 = 0; double m0v = pa[0];
        #pragma unroll
        for (int e = 1; e < NEXP; ++e) if (pa[e] > m0v) { m0v = pa[e]; i0 = e; }  // strict >: lax.top_k ties
        int i1 = -1; double m1v = -1e300;
        #pragma unroll
        for (int e = 0; e < NEXP; ++e) if (e != i0 && pa[e] > m1v) { m1v = pa[e]; i1 = e; }
        float d  = (float)(m1v - m0v);
        float e1 = expf(d);
        float inv = 1.0f / (1.0f + e1);                  // gate of i0; gate of i1 = e1*inv

        int a  = i0 < i1 ? i0 : i1;
        int b2 = i0 < i1 ? i1 : i0;
        int p  = a * 4 - ((a * (a - 1)) >> 1) + (b2 - a - 1);
        float ga = (a == i0) ? inv : e1 * inv;           // gate of lower-indexed expert
        float gb = (a == i0) ? e1 * inv : inv;

        unsigned long long below = (1ull << lane) - 1ull;
        int myrank = 0, myh = 0;
        #pragma unroll
        for (int e = 0; e < NPAIR; ++e) {
            unsigned long long mask = __ballot(p == e);
            if (p == e)    myrank = (int)__popcll(mask & below);
            if (lane == e) myh    = (int)__popcll(mask);
        }
        tmeta[tok0 + lane] = p | (myrank << 8);          // p<10, rank<64
        tgate[tok0 + lane] = make_float2(ga, gb);
        if (lane < NPAIR) blkcnt[lane * NBLK + blockIdx.x] = myh;
    }
}

// ---------------- Kernel 2: FUSED scan+scatter+convert ------------------------------
// Round-5 diagnosis: total(246.9) - moe(71.1) = 175.8us residual, yet no non-moe
// kernel exceeds 70.96us (top-5 cutoff) and floor estimates for scan/scatter/convert
// sum to ~15us -- the residual hides in several sub-cutoff kernels + 5-deep launch
// serialization. Fix: ONE kernel, grid 436: blocks 0..255 scatter tokens (each block
// redundantly computes its 10 pair-prefixes over blkcnt -- <=40KB reads, ~us); block
// 255 also writes cnt[]; blocks 256..435 run the unchanged We transpose/bf16 convert.
// 5 launches -> 3; convert overlaps scatter instead of serializing after it.
__global__ __launch_bounds__(256) void mid_kernel(const int* __restrict__ blkcnt,
                                                  const int* __restrict__ tmeta,
                                                  int* __restrict__ bidx,
                                                  int* __restrict__ cnt,
                                                  const float* __restrict__ We,
                                                  unsigned short* __restrict__ WeT) {
    __shared__ float tile[64][65];                       // convert branch (16.6 KB)
    __shared__ int   sbase[NPAIR][4];                    // scatter branch
    __shared__ int   rred[4];
    int bid = blockIdx.x;
    int t = threadIdx.x;

    if (bid >= 256) {
        // ---- convert part: We[e][c][d] fp32 -> WeT[e][d][c] bf16 (tiled transpose)
        int idx = bid - 256;                             // 0..179
        int e   = idx / 36, rem = idx % 36;
        int c0  = (rem / 6) * 64, d0 = (rem % 6) * 64;
        const float* src = We + (size_t)e * WE_STRIDE;
        int dr = t & 15, cr = t >> 4;
        for (int s = 0; s < 64; s += 16) {
            float4 v = *(const float4*)&src[(size_t)(c0 + cr + s) * CDIM + d0 + dr * 4];
            tile[cr + s][dr * 4 + 0] = v.x;
            tile[cr + s][dr * 4 + 1] = v.y;
            tile[cr + s][dr * 4 + 2] = v.z;
            tile[cr + s][dr * 4 + 3] = v.w;
        }
        __syncthreads();
        unsigned short* dst = WeT + (size_t)e * WE_STRIDE;
        int c4 = t & 15, drow = t >> 4;
        for (int s = 0; s < 64; s += 16) {
            int d = drow + s;
            ushort4 o;
            o.x = f2bf(tile[c4 * 4 + 0][d]);
            o.y = f2bf(tile[c4 * 4 + 1][d]);
            o.z = f2bf(tile[c4 * 4 + 2][d]);
            o.w = f2bf(tile[c4 * 4 + 3][d]);
            *(ushort4*)&dst[(size_t)(d0 + d) * CDIM + c0 + c4 * 4] = o;
        }
        return;
    }

    // ---- scatter part: tokens [bid*256, bid*256+256) = token-blocks 4b..4b+3 ------
    int lane = t & 63, w = t >> 6;
    int nb4 = bid * 4;
    for (int p = 0; p < NPAIR; ++p) {
        int s = 0;
        for (int j = t; j < nb4; j += 256) s += blkcnt[p * NBLK + j];
        #pragma unroll
        for (int d = 1; d < 64; d <<= 1) s += __shfl_xor(s, d);      // full-wave sum
        if (lane == 0) rred[w] = s;
        __syncthreads();
        if (t == 0) {
            int S  = rred[0] + rred[1] + rred[2] + rred[3];          // excl prefix before tb=4b
            int c0_ = blkcnt[p * NBLK + nb4 + 0];
            int c1_ = blkcnt[p * NBLK + nb4 + 1];
            int c2_ = blkcnt[p * NBLK + nb4 + 2];
            sbase[p][0] = S;
            sbase[p][1] = S + c0_;
            sbase[p][2] = S + c0_ + c1_;
            sbase[p][3] = S + c0_ + c1_ + c2_;
            if (bid == 255) cnt[p] = S + c0_ + c1_ + c2_ + blkcnt[p * NBLK + nb4 + 3];
        }
        __syncthreads();                                 // sbase ready; rred reusable
    }
    int tok  = bid * 256 + t;
    int meta = tmeta[tok];
    int p    = meta & 255, rank = meta >> 8;
    int pos  = sbase[p][t >> 6] + rank;
    if (pos < CAP) bidx[p * CAP + pos] = tok;
}

// ---------------- Kernel 3: grouped gathered GEMM, 128x128, counted-vmcnt pipeline --
// Unchanged from round 5 except T5: s_setprio(1/0) around the MFMA cluster (neutral
// semantics; 2 blocks/CU give the scheduler wave-role diversity to arbitrate).
__global__ __launch_bounds__(512, 4) void moe_kernel(const float* __restrict__ x,
                                                     const unsigned short* __restrict__ WeT,
                                                     const int* __restrict__ cnt,
                                                     const int* __restrict__ bidx,
                                                     const float2* __restrict__ tgate,
                                                     const float* __restrict__ be,
                                                     float* __restrict__ out) {
    // grid 1920 = 8*240: bijective XCD-chunk swizzle
    int bh  = blockIdx.x;
    int bid = (bh & 7) * 240 + (bh >> 3);
    int pq  = bid / 3;                    // p*64 + mt
    int nt  = bid - pq * 3;
    int p   = pq >> 6;
    int mt  = pq & 63;

    int nct = cnt[p];
    int m0  = mt * 128;
    if (m0 >= nct) return;                // block-uniform early exit (before any barrier)
    int valid = nct - m0; if (valid > 128) valid = 128;

    int ea = PAIR_A[p], eb = PAIR_B[p];
    int n0 = nt * 128;
    int t = threadIdx.x, lane = t & 63, wid = t >> 6;
    int wm = wid >> 1, wn = wid & 1;      // 4(m) x 2(n) waves -> wave tile 32x64
    int q = lane >> 4, cc = lane & 15;

    // granules (16B): A dbuf 0..1023 (512/buf), B tribuf 1024..4095 (1024/buf) = 64 KB
    __shared__ __align__(16) unsigned short S[4096 * 8];

    floatx4 acc[2][2][4];                 // [expert a/b][m-sub][n-sub]
    #pragma unroll
    for (int e = 0; e < 2; ++e)
        #pragma unroll
        for (int i = 0; i < 2; ++i)
            #pragma unroll
            for (int j = 0; j < 4; ++j)
                acc[e][i][j] = (floatx4){0.0f, 0.0f, 0.0f, 0.0f};

    // B staging via DMA: 1024 granules/kc, 2/thread (expert a and expert b halves)
    int rrow = t >> 2, gp = t & 3;
    int gl = (gp - (rrow >> 1)) & 3;      // conflict-free k-granule perm (verified)
    const unsigned short* bsrcA = WeT + (size_t)ea * WE_STRIDE + (size_t)(n0 + rrow) * CDIM + gl * 8;
    const unsigned short* bsrcB = WeT + (size_t)eb * WE_STRIDE + (size_t)(n0 + rrow) * CDIM + gl * 8;
    int bdstA = wid * 64;                 // granule within B buf (+lane via DMA)
    int bdstB = 512 + wid * 64;

    // A staging: thread -> (gathered row, 16B piece), swizzled dest granule
    int srow = t >> 2, sp = t & 3;
    int arow = m0 + (srow < valid ? srow : valid - 1);   // clamp: ragged last tile
    int gi = bidx[p * CAP + arow];
    const float* xrow = x + (size_t)gi * CDIM + sp * 8;
    int agr = 4 * srow + ((sp + (srow >> 1)) & 3);       // + buf*512

    // fragment read bases (loop-invariant perm: (row>>1)&3 == (cc>>1)&3)
    int perm = (q + (cc >> 1)) & 3;
    int a_gr = 4 * (wm * 32 + cc) + perm;                // + 64*i + buf*512
    int b_gr = 4 * (wn * 64 + cc) + perm;                // + 512*e + 64*j + bufbase

    // prologue: x0,x1 regs (issued BEFORE the B DMAs); DMA B0->buf0, B1->buf1
    float4 xreg[2][2];
    xreg[0][0] = *(const float4*)(xrow);
    xreg[0][1] = *(const float4*)(xrow + 4);
    xreg[1][0] = *(const float4*)(xrow + 32);
    xreg[1][1] = *(const float4*)(xrow + 36);
    load_lds16(bsrcA,      S + (size_t)(1024 + bdstA) * 8);
    load_lds16(bsrcB,      S + (size_t)(1024 + bdstB) * 8);
    load_lds16(bsrcA + 32, S + (size_t)(2048 + bdstA) * 8);
    load_lds16(bsrcB + 32, S + (size_t)(2048 + bdstB) * 8);

    #pragma unroll
    for (int kc = 0; kc < 12; ++kc) {
        int buf = kc & 1;                 // A buffer
        int bb  = kc - (kc / 3) * 3;      // B buffer (kc%3, constant-folded)
        // convert x[kc] -> As[buf]
        float4 a0 = xreg[buf][0], a1 = xreg[buf][1];
        short8 av;
        av[0] = f2bf(a0.x); av[1] = f2bf(a0.y); av[2] = f2bf(a0.z); av[3] = f2bf(a0.w);
        av[4] = f2bf(a1.x); av[5] = f2bf(a1.y); av[6] = f2bf(a1.z); av[7] = f2bf(a1.w);
        *(short8*)&S[(size_t)(buf * 512 + agr) * 8] = av;

        // counted-vmcnt barrier: B[kc] landed, {x[kc+1],B[kc+1]} stay in flight
        if (kc == 0 || kc == 11) {
            asm volatile("s_waitcnt vmcnt(0) lgkmcnt(0)" ::: "memory");
        } else {
            asm volatile("s_waitcnt vmcnt(4) lgkmcnt(0)" ::: "memory");
        }
        __builtin_amdgcn_s_barrier();
        __builtin_amdgcn_sched_barrier(0);

        if (kc < 10) {                    // issue kc+2 prefetch (x first, then B-DMA)
            int k2 = (kc + 2) * 32;
            int nb = (kc + 2) % 3;
            xreg[buf][0] = *(const float4*)(xrow + k2);
            xreg[buf][1] = *(const float4*)(xrow + k2 + 4);
            load_lds16(bsrcA + k2, S + (size_t)(1024 + nb * 1024 + bdstA) * 8);
            load_lds16(bsrcB + k2, S + (size_t)(1024 + nb * 1024 + bdstB) * 8);
        }

        int ao = buf * 512, bo = 1024 + bb * 1024;
        short8 af0 = *(const short8*)&S[(size_t)(ao + a_gr) * 8];
        short8 af1 = *(const short8*)&S[(size_t)(ao + a_gr + 64) * 8];
        __builtin_amdgcn_s_setprio(1);    // T5: favor MFMA-issuing wave
        #pragma unroll
        for (int e = 0; e < 2; ++e) {
            #pragma unroll
            for (int j = 0; j < 4; ++j) {
                short8 bf = *(const short8*)&S[(size_t)(bo + b_gr + e * 512 + j * 64) * 8];
                acc[e][0][j] = __builtin_amdgcn_mfma_f32_16x16x32_bf16(af0, bf, acc[e][0][j], 0, 0, 0);
                acc[e][1][j] = __builtin_amdgcn_mfma_f32_16x16x32_bf16(af1, bf, acc[e][1][j], 0, 0, 0);
            }
        }
        __builtin_amdgcn_s_setprio(0);
    }

    // ---- epilogue: gates+indices to LDS, combine + bias + leaky, scatter store -----
    __syncthreads();                      // full drain before reusing S
    float2* Gp = (float2*)S;                             // 128 * 8B = 1 KB
    int*    Ip = (int*)((char*)S + 1024);                // 128 * 4B
    if (t < 128) {
        int rr = m0 + (t < valid ? t : valid - 1);
        int gid = bidx[p * CAP + rr];
        Ip[t] = gid;
        Gp[t] = tgate[gid];
    }
    float ba_[4], bb_[4];
    #pragma unroll
    for (int j = 0; j < 4; ++j) {
        int oc = n0 + wn * 64 + j * 16 + cc;
        ba_[j] = be[ea * CDIM + oc];
        bb_[j] = be[eb * CDIM + oc];
    }
    __syncthreads();

    #pragma unroll
    for (int i = 0; i < 2; ++i) {
        #pragma unroll
        for (int rr4 = 0; rr4 < 4; ++rr4) {
            int trow = wm * 32 + i * 16 + q * 4 + rr4;   // C/D: col=cc, row=q*4+rr4
            if (trow < valid) {
                float2 g = Gp[trow];
                int gid  = Ip[trow];
                #pragma unroll
                for (int j = 0; j < 4; ++j) {
                    int oc = n0 + wn * 64 + j * 16 + cc;
                    float v = g.x * (acc[0][i][j][rr4] + ba_[j])
                            + g.y * (acc[1][i][j][rr4] + bb_[j]);
                    v = v > 0.0f ? v : 0.01f * v;
                    out[(size_t)gid * CDIM + oc] = v;
                }
            }
        }
    }
}

extern "C" void kernel_launch(void* const* d_in, const int* in_sizes, int n_in,
                              void* d_out, int out_size, void* d_ws, size_t ws_size,
                              hipStream_t stream) {
    const float* x  = (const float*)d_in[0];
    const float* Wg = (const float*)d_in[1];
    const float* We = (const float*)d_in[2];
    const float* be = (const float*)d_in[3];
    float* out = (float*)d_out;

    // ws layout (16B-aligned sections), total ~2.67 MB:
    //   cnt[10]            @ 0       (pad 256)
    //   bidx  10*8192*4    @ 256         = 327680
    //   blkcnt 10*1024*4   @ 327936      = 40960
    //   (gap: former bbase)@ 368896      = 40960
    //   tmeta  65536*4     @ 409856      = 262144
    //   tgate  65536*8     @ 672000      = 524288
    //   WeT    5*384*384*2 @ 1196288     = 1474560
    char* ws = (char*)d_ws;
    int*            cnt    = (int*)ws;
    int*            bidx   = (int*)(ws + 256);
    int*            blkcnt = (int*)(ws + 327936);
    int*            tmeta  = (int*)(ws + 409856);
    float2*         tgate  = (float2*)(ws + 672000);
    unsigned short* WeT    = (unsigned short*)(ws + 1196288);

    router_kernel<<<NBLK, 256, 0, stream>>>(x, Wg, blkcnt, tmeta, tgate);
    mid_kernel<<<436, 256, 0, stream>>>(blkcnt, tmeta, bidx, cnt, We, WeT);
    moe_kernel<<<NPAIR * 64 * 3, 512, 0, stream>>>(x, WeT, cnt, bidx, tgate, be, out);
}